// Round 1
// baseline (18698.341 us; speedup 1.0000x reference)
//
#include <hip/hip_runtime.h>

#define NB 4
#define NC 3
#define BC 12
#define HW 65536
#define KCAP 32
#define MAXI 5

typedef unsigned long long u64;

// ---------------- union-find (lock-free, link-to-min, path halving) ----------------
__device__ __forceinline__ int uf_find(int* P, int x){
  while (true){
    int p = P[x];
    if (p == x) return x;
    int gp = P[p];
    if (gp == p) return p;
    P[x] = gp;   // path halving: write ancestor, always safe
    x = gp;
  }
}
__device__ __forceinline__ int uf_root(const int* P, int x){
  int p = P[x];
  while (p != x){ x = p; p = P[x]; }
  return x;
}
__device__ __forceinline__ void uf_union(int* P, int a, int b){
  while (true){
    a = uf_find(P, a); b = uf_find(P, b);
    if (a == b) return;
    if (a < b){ int t = a; a = b; b = t; }   // a > b: link larger root to smaller
    int old = atomicCAS(&P[a], a, b);
    if (old == a) return;
    a = old;
  }
}

// ---------------- binarization ----------------
__global__ void k_bin_pred(const float* __restrict__ pred, const float* __restrict__ gum,
                           unsigned char* __restrict__ mask){
  int g = blockIdx.x * 256 + threadIdx.x;
  if (g >= NB * HW) return;
  int b = g >> 16, p = g & (HW - 1);
  size_t base = (size_t)b * NC * HW + p;
  float v0 = pred[base]          + gum[base];
  float v1 = pred[base + HW]     + gum[base + HW];
  float v2 = pred[base + 2*HW]   + gum[base + 2*HW];
  int a = 0; float m = v0;
  if (v1 > m){ m = v1; a = 1; }
  if (v2 > m){ m = v2; a = 2; }
  mask[base]        = (a == 0);
  mask[base + HW]   = (a == 1);
  mask[base + 2*HW] = (a == 2);
}

__global__ void k_bin_tgt(const int* __restrict__ tgt, unsigned char* __restrict__ mask){
  int g = blockIdx.x * 256 + threadIdx.x;
  if (g >= NB * HW) return;
  int b = g >> 16, p = g & (HW - 1);
  int t = tgt[(size_t)b * HW + p];
  size_t base = (size_t)b * NC * HW + p;
  mask[base]        = (t == 0);
  mask[base + HW]   = (t == 1);
  mask[base + 2*HW] = (t == 2);
}

// erode_flag=1: all 25 in 5x5 window (zero-padded); 0: any
__global__ void k_morph(const unsigned char* __restrict__ in, unsigned char* __restrict__ out,
                        int erode_flag){
  int g = blockIdx.x * 256 + threadIdx.x;
  if (g >= BC * HW) return;
  int s = g >> 16, p = g & (HW - 1);
  int y = p >> 8, x = p & 255;
  const unsigned char* im = in + ((size_t)s << 16);
  int cnt = 0;
  for (int dy = -2; dy <= 2; dy++){
    int yy = y + dy;
    if (yy < 0 || yy > 255) continue;
    for (int dx = -2; dx <= 2; dx++){
      int xx = x + dx;
      if (xx < 0 || xx > 255) continue;
      cnt += im[yy * 256 + xx];
    }
  }
  out[g] = erode_flag ? (cnt == 25) : (cnt > 0);
}

// ---------------- connected components ----------------
__global__ void k_cc_init(int* __restrict__ parent){
  int g = blockIdx.x * 256 + threadIdx.x;
  if (g >= BC * HW) return;
  parent[g] = g & (HW - 1);
}

__global__ void k_cc_merge(const unsigned char* __restrict__ mask, int* __restrict__ parent){
  int g = blockIdx.x * 256 + threadIdx.x;
  if (g >= BC * HW) return;
  if (!mask[g]) return;
  int s = g >> 16, p = g & (HW - 1);
  int y = p >> 8, x = p & 255;
  int* P = parent + ((size_t)s << 16);
  const unsigned char* im = mask + ((size_t)s << 16);
  if (y > 0){
    if (x > 0   && im[p - 257]) uf_union(P, p, p - 257);
    if (           im[p - 256]) uf_union(P, p, p - 256);
    if (x < 255 && im[p - 255]) uf_union(P, p, p - 255);
  }
  if (x > 0 && im[p - 1]) uf_union(P, p, p - 1);
}

__global__ void k_cc_flatten(int* __restrict__ parent){
  int g = blockIdx.x * 256 + threadIdx.x;
  if (g >= BC * HW) return;
  int s = g >> 16, p = g & (HW - 1);
  int* P = parent + ((size_t)s << 16);
  int r = uf_find(P, p);
  P[p] = r;
}

// per-root max pixel index (the reference's label), plus global max foreground idx
__global__ void k_comp_max(const unsigned char* __restrict__ mask, const int* __restrict__ parent,
                           int* __restrict__ comp, int* __restrict__ maxIdx){
  int g = blockIdx.x * 256 + threadIdx.x;
  if (g >= BC * HW) return;
  int s = g >> 16, p = g & (HW - 1);
  bool fg = mask[g] != 0;
  const int* P = parent + ((size_t)s << 16);
  int r = fg ? uf_root(P, p) : -1;
  u64 act = __ballot(fg);
  if (act == 0) return;
  int lane = threadIdx.x & 63;
  int hi = 63 - __clzll(act);
  if (lane == hi) atomicMax(&maxIdx[s], p);   // p ascends with lane within wave
  int rref = __shfl(r, hi);
  bool uni = __all((!fg) || (r == rref));
  if (uni){
    if (lane == hi) atomicMax(&comp[((size_t)s << 16) + rref], p);
  } else if (fg){
    atomicMax(&comp[((size_t)s << 16) + r], p);
  }
}

__global__ void k_lab(const unsigned char* __restrict__ mask, const int* __restrict__ parent,
                      const int* __restrict__ comp, int* __restrict__ Lab){
  int g = blockIdx.x * 256 + threadIdx.x;
  if (g >= BC * HW) return;
  int s = g >> 16, p = g & (HW - 1);
  int v = 0;
  if (mask[g]){
    const int* P = parent + ((size_t)s << 16);
    v = comp[((size_t)s << 16) + uf_root(P, p)];
  }
  Lab[g] = v;
}

__global__ void k_count(const unsigned char* __restrict__ mask, const int* __restrict__ Lab,
                        int* __restrict__ sizes){
  int g = blockIdx.x * 256 + threadIdx.x;
  if (g >= BC * HW) return;
  int s = g >> 16;
  bool fg = mask[g] != 0;
  int l = fg ? Lab[g] : -1;
  u64 act = __ballot(fg);
  if (act == 0) return;
  int lane = threadIdx.x & 63;
  int hi = 63 - __clzll(act);
  int lref = __shfl(l, hi);
  bool uni = __all((!fg) || (l == lref));
  if (uni){
    if (lane == hi) atomicAdd(&sizes[((size_t)s << 16) + lref], __popcll(act));
  } else if (fg){
    atomicAdd(&sizes[((size_t)s << 16) + l], 1);
  }
}

// ---------------- top-32 selection per slot (matches lax.top_k w/ tie->lower idx) ----------------
__global__ void k_select(const int* __restrict__ Lab, const int* __restrict__ sizes,
                         const int* __restrict__ maxIdx,
                         int* __restrict__ labSel, float* __restrict__ sSel,
                         float* __restrict__ scaleSel){
  int s = blockIdx.x;
  int tid = threadIdx.x;
  const int* L  = Lab   + ((size_t)s << 16);
  const int* SZ = sizes + ((size_t)s << 16);
  __shared__ int sel[KCAP];
  __shared__ float rk[256];
  __shared__ int   ri[256];
  int mi = maxIdx[s];
  float maxLf = (float)(mi >= 1 ? mi : 1);
  for (int r = 0; r < KCAP; r++){
    float bk = -1.0f; int bi = 0x7fffffff;
    for (int p = tid; p < HW; p += 256){
      if (L[p] == p && p > 0){           // root pixel (label == own index, label>0)
        bool used = false;
        for (int q = 0; q < r; q++) if (sel[q] == p){ used = true; break; }
        if (!used){
          float key = (float)SZ[p] * (float)p;
          if (key > bk || (key == bk && p < bi)){ bk = key; bi = p; }
        }
      }
    }
    rk[tid] = bk; ri[tid] = bi;
    __syncthreads();
    for (int off = 128; off > 0; off >>= 1){
      if (tid < off){
        if (rk[tid+off] > rk[tid] || (rk[tid+off] == rk[tid] && ri[tid+off] < ri[tid])){
          rk[tid] = rk[tid+off]; ri[tid] = ri[tid+off];
        }
      }
      __syncthreads();
    }
    if (tid == 0){
      if (rk[0] > 0.0f){
        int lab = ri[0];
        sel[r] = lab;
        labSel[s*KCAP + r]   = lab;
        float v = (float)lab;
        sSel[s*KCAP + r]     = (float)SZ[lab] * v / maxLf;
        scaleSel[s*KCAP + r] = v / maxLf;
      } else {
        sel[r] = -1;
        for (int q = r; q < KCAP; q++){
          labSel[s*KCAP + q] = -1;
          sSel[s*KCAP + q] = 0.0f;
          scaleSel[s*KCAP + q] = 0.0f;
        }
      }
    }
    __syncthreads();
    if (sel[r] == -1) break;
  }
}

// ---------------- build bitmaps of the 32 new components ----------------
__global__ void k_newbm(const int* __restrict__ Lab, const int* __restrict__ labSel,
                        u64* __restrict__ newbm){
  int s = blockIdx.x >> 2;                     // 4 blocks per slot
  int w = (blockIdx.x & 3) * 256 + threadIdx.x; // word index 0..1023
  __shared__ int sel[KCAP];
  if (threadIdx.x < KCAP) sel[threadIdx.x] = labSel[s*KCAP + threadIdx.x];
  __syncthreads();
  int l[64];
  const int* Ls = Lab + ((size_t)s << 16) + (w << 6);
  #pragma unroll
  for (int i = 0; i < 64; i++) l[i] = Ls[i];
  u64* out = newbm + (size_t)s * KCAP * 1024 + w;
  for (int j = 0; j < KCAP; j++){
    int lj = sel[j];
    u64 m = 0;
    if (lj > 0){
      #pragma unroll
      for (int i = 0; i < 64; i++) m |= ((u64)(l[i] == lj)) << i;
    }
    out[(size_t)j * 1024] = m;
  }
}

// ---------------- overlaps: OV[s][j][k] = scale_j*scaleP_k*popc(new_j & P_k) ----------------
__global__ void k_overlap(const u64* __restrict__ nb, const u64* __restrict__ pb,
                          const float* __restrict__ scaleSel, const float* __restrict__ scaleP,
                          float* __restrict__ OV){
  int bid = blockIdx.x;                 // s*1024 + j*32 + k
  int s = bid >> 10, j = (bid >> 5) & 31, k = bid & 31;
  float sn = scaleSel[s*KCAP + j], sp = scaleP[s*KCAP + k];
  int t = threadIdx.x;
  if (sn == 0.0f || sp == 0.0f){
    if (t == 0) OV[bid] = 0.0f;
    return;
  }
  const u64* A  = nb + (size_t)(s*KCAP + j) * 1024;
  const u64* Bm = pb + (size_t)(s*KCAP + k) * 1024;
  int cnt = 0;
  for (int w = t; w < 1024; w += 64) cnt += __popcll(A[w] & Bm[w]);
  #pragma unroll
  for (int off = 32; off > 0; off >>= 1) cnt += __shfl_down(cnt, off);
  if (t == 0) OV[bid] = sn * sp * (float)cnt;
}

// ---------------- sequential matching scan (mirrors lax.scan) ----------------
__global__ void k_update(const float* __restrict__ OV, const int* __restrict__ labSel,
                         const float* __restrict__ sSel, const float* __restrict__ scaleSel,
                         float* __restrict__ bar, int* __restrict__ nArr,
                         float* __restrict__ scaleP,
                         const u64* __restrict__ newbm, u64* __restrict__ Pbm, int t){
  int s = blockIdx.x;
  __shared__ int add_dst[KCAP];
  if (threadIdx.x == 0){
    int n = nArr[s];
    for (int j = 0; j < KCAP; j++){
      add_dst[j] = -1;
      if (labSel[s*KCAP + j] < 0) continue;     // invalid comp: no-op
      const float* ov = OV + s*1024 + j*32;
      int best = 0; float bv = ov[0];
      for (int k = 1; k < KCAP; k++){ float v = ov[k]; if (v > bv){ bv = v; best = k; } }
      if (bv > 0.0f){                            // matched: overwrite stored slot's bar at t
        bar[(s*KCAP + best)*MAXI + t] = sSel[s*KCAP + j];
      } else if (n < KCAP){                      // add new component
        bar[(s*KCAP + n)*MAXI + t] = sSel[s*KCAP + j];
        scaleP[s*KCAP + n] = scaleSel[s*KCAP + j];
        add_dst[j] = n;
        n++;
      }
    }
    nArr[s] = n;
  }
  __syncthreads();
  for (int j = 0; j < KCAP; j++){
    int d = add_dst[j];
    if (d < 0) continue;
    const u64* src = newbm + (size_t)(s*KCAP + j) * 1024;
    u64* dst       = Pbm   + (size_t)(s*KCAP + d) * 1024;
    for (int w = threadIdx.x; w < 1024; w += blockDim.x) dst[w] = src[w];
  }
}

// ---------------- final loss ----------------
__global__ void k_loss(const float* __restrict__ barP, const float* __restrict__ barT,
                       const int* __restrict__ nP, const int* __restrict__ nT,
                       float* __restrict__ out){
  if (blockIdx.x != 0 || threadIdx.x != 0) return;
  float total = 0.0f;
  for (int s = 0; s < BC; s++){
    int np = nP[s], nt = nT[s];
    for (int k = 0; k < KCAP; k++){
      if (k >= np) continue;
      const float* bp = barP + (s*KCAP + k)*MAXI;
      float pmax = bp[0];
      for (int t = 1; t < MAXI; t++) pmax = fmaxf(pmax, bp[t]);
      if (!(pmax > 0.0f)) pmax = 1.0f;
      float acc = 0.0f;
      for (int t = 0; t < MAXI; t++){
        float tv = (k < nt) ? barT[(s*KCAP + k)*MAXI + t] : 0.0f;
        float d = tv - bp[t];
        acc += d * d;
      }
      total += acc / (pmax * pmax);
    }
  }
  out[0] = total * 0.25f;   // mean over B=4
}

extern "C" void kernel_launch(void* const* d_in, const int* in_sizes, int n_in,
                              void* d_out, int out_size, void* d_ws, size_t ws_size,
                              hipStream_t stream){
  const float* pred = (const float*)d_in[0];
  const float* gum  = (const float*)d_in[1];
  const int*   tgt  = (const int*)d_in[2];
  float* out = (float*)d_out;
  char* ws = (char*)d_ws;
  size_t off = 0;
  auto alloc = [&](size_t bytes)->char*{
    char* p = ws + off;
    off += (bytes + 255) & ~(size_t)255;
    return p;
  };
  unsigned char* maskBase = (unsigned char*)alloc(BC*HW);
  unsigned char* maskA    = (unsigned char*)alloc(BC*HW);
  unsigned char* maskB    = (unsigned char*)alloc(BC*HW);
  int* parent  = (int*)alloc((size_t)BC*HW*4);
  int* compsz  = (int*)alloc((size_t)BC*HW*4);   // comp-max, then reused as sizes
  int* Lab     = (int*)alloc((size_t)BC*HW*4);
  u64* newbm   = (u64*)alloc((size_t)BC*KCAP*1024*8);
  u64* Pbm     = (u64*)alloc((size_t)BC*KCAP*1024*8);
  float* scaleP   = (float*)alloc(BC*KCAP*4);
  int*   labSel   = (int*)alloc(BC*KCAP*4);
  float* sSel     = (float*)alloc(BC*KCAP*4);
  float* scaleSel = (float*)alloc(BC*KCAP*4);
  float* OV       = (float*)alloc(BC*KCAP*KCAP*4);
  int*   maxIdx   = (int*)alloc(BC*4);
  float* barP     = (float*)alloc(BC*KCAP*MAXI*4);
  float* barT     = (float*)alloc(BC*KCAP*MAXI*4);
  int*   nP       = (int*)alloc(BC*4);
  int*   nT       = (int*)alloc(BC*4);
  if (off > ws_size) return;   // workspace too small -> fail loudly in validation

  const int PIXBLK = (BC*HW)/256;   // 3072
  const int BINBLK = (NB*HW)/256;   // 1024

  auto process = [&](const unsigned char* m, int t, float* bar, int* nArr){
    k_cc_init<<<PIXBLK,256,0,stream>>>(parent);
    k_cc_merge<<<PIXBLK,256,0,stream>>>(m, parent);
    k_cc_flatten<<<PIXBLK,256,0,stream>>>(parent);
    hipMemsetAsync(compsz, 0, (size_t)BC*HW*4, stream);
    hipMemsetAsync(maxIdx, 0, BC*4, stream);
    k_comp_max<<<PIXBLK,256,0,stream>>>(m, parent, compsz, maxIdx);
    k_lab<<<PIXBLK,256,0,stream>>>(m, parent, compsz, Lab);
    hipMemsetAsync(compsz, 0, (size_t)BC*HW*4, stream);
    k_count<<<PIXBLK,256,0,stream>>>(m, Lab, compsz);
    k_select<<<BC,256,0,stream>>>(Lab, compsz, maxIdx, labSel, sSel, scaleSel);
    k_newbm<<<BC*4,256,0,stream>>>(Lab, labSel, newbm);
    k_overlap<<<BC*KCAP*KCAP,64,0,stream>>>(newbm, Pbm, scaleSel, scaleP, OV);
    k_update<<<BC,256,0,stream>>>(OV, labSel, sSel, scaleSel, bar, nArr, scaleP, newbm, Pbm, t);
  };

  for (int pass = 0; pass < 2; pass++){
    float* bar = pass ? barT : barP;
    int* nArr  = pass ? nT : nP;
    hipMemsetAsync(bar, 0, BC*KCAP*MAXI*4, stream);
    hipMemsetAsync(nArr, 0, BC*4, stream);
    hipMemsetAsync(Pbm, 0, (size_t)BC*KCAP*1024*8, stream);
    hipMemsetAsync(scaleP, 0, BC*KCAP*4, stream);
    if (pass == 0) k_bin_pred<<<BINBLK,256,0,stream>>>(pred, gum, maskBase);
    else           k_bin_tgt<<<BINBLK,256,0,stream>>>(tgt, maskBase);
    // schedule: (binary,2), (e1,3), (e2,4), (d1,1), (d2,0)
    process(maskBase, 2, bar, nArr);
    k_morph<<<PIXBLK,256,0,stream>>>(maskBase, maskA, 1);
    process(maskA, 3, bar, nArr);
    k_morph<<<PIXBLK,256,0,stream>>>(maskA, maskB, 1);
    process(maskB, 4, bar, nArr);
    k_morph<<<PIXBLK,256,0,stream>>>(maskBase, maskA, 0);
    process(maskA, 1, bar, nArr);
    k_morph<<<PIXBLK,256,0,stream>>>(maskA, maskB, 0);
    process(maskB, 0, bar, nArr);
  }
  k_loss<<<1,64,0,stream>>>(barP, barT, nP, nT, out);
}

// Round 2
// 3444.321 us; speedup vs baseline: 5.4287x; 5.4287x over previous
//
#include <hip/hip_runtime.h>

#define NB 4
#define NC 3
#define BC 12
#define HW 65536
#define KCAP 32
#define MAXI 5
#define MAXROOTS 16384

typedef unsigned long long u64;

// ---------------- union-find (lock-free, link-to-min, path halving) ----------------
__device__ __forceinline__ int uf_find(int* P, int x){
  while (true){
    int p = P[x];
    if (p == x) return x;
    int gp = P[p];
    if (gp == p) return p;
    P[x] = gp;   // path halving
    x = gp;
  }
}
__device__ __forceinline__ void uf_union(int* P, int a, int b){
  while (true){
    a = uf_find(P, a); b = uf_find(P, b);
    if (a == b) return;
    if (a < b){ int t = a; a = b; b = t; }   // link larger root to smaller
    int old = atomicCAS(&P[a], a, b);
    if (old == a) return;
    a = old;
  }
}

// ---------------- binarization ----------------
__global__ void k_bin_pred(const float* __restrict__ pred, const float* __restrict__ gum,
                           unsigned char* __restrict__ mask){
  int g = blockIdx.x * 256 + threadIdx.x;
  if (g >= NB * HW) return;
  int b = g >> 16, p = g & (HW - 1);
  size_t base = (size_t)b * NC * HW + p;
  float v0 = pred[base]          + gum[base];
  float v1 = pred[base + HW]     + gum[base + HW];
  float v2 = pred[base + 2*HW]   + gum[base + 2*HW];
  int a = 0; float m = v0;
  if (v1 > m){ m = v1; a = 1; }
  if (v2 > m){ m = v2; a = 2; }
  mask[base]        = (a == 0);
  mask[base + HW]   = (a == 1);
  mask[base + 2*HW] = (a == 2);
}

__global__ void k_bin_tgt(const int* __restrict__ tgt, unsigned char* __restrict__ mask){
  int g = blockIdx.x * 256 + threadIdx.x;
  if (g >= NB * HW) return;
  int b = g >> 16, p = g & (HW - 1);
  int t = tgt[(size_t)b * HW + p];
  size_t base = (size_t)b * NC * HW + p;
  mask[base]        = (t == 0);
  mask[base + HW]   = (t == 1);
  mask[base + 2*HW] = (t == 2);
}

// erode_flag=1: all 25 in 5x5 window (zero-padded); 0: any
__global__ void k_morph(const unsigned char* __restrict__ in, unsigned char* __restrict__ out,
                        int erode_flag){
  int g = blockIdx.x * 256 + threadIdx.x;
  if (g >= BC * HW) return;
  int s = g >> 16, p = g & (HW - 1);
  int y = p >> 8, x = p & 255;
  const unsigned char* im = in + ((size_t)s << 16);
  int cnt = 0;
  for (int dy = -2; dy <= 2; dy++){
    int yy = y + dy;
    if (yy < 0 || yy > 255) continue;
    for (int dx = -2; dx <= 2; dx++){
      int xx = x + dx;
      if (xx < 0 || xx > 255) continue;
      cnt += im[yy * 256 + xx];
    }
  }
  out[g] = erode_flag ? (cnt == 25) : (cnt > 0);
}

// ---------------- stage 1: per-64x64-tile local CC in LDS ----------------
// also zeroes comp/sizes for its tile and (tile 0) maxIdx/cnt for the slot
__global__ void k_cc_local(const unsigned char* __restrict__ mask, int* __restrict__ parent,
                           int* __restrict__ comp, int* __restrict__ sizes,
                           int* __restrict__ maxIdx, int* __restrict__ cnt){
  __shared__ int lp[4096];
  __shared__ u64 mb[64];
  int s = blockIdx.x >> 4;
  int tile = blockIdx.x & 15;
  int ty = tile >> 2, tx = tile & 3;
  int y0 = ty * 64, x0 = tx * 64;
  int t = threadIdx.x;
  size_t sbase = (size_t)s << 16;
  if (t < 64){
    const u64* mrow = (const u64*)(mask + sbase + (size_t)(y0 + t) * 256 + x0);
    u64 bits = 0;
    #pragma unroll
    for (int k = 0; k < 8; k++){
      u64 v = mrow[k];
      #pragma unroll
      for (int b = 0; b < 8; b++) bits |= ((v >> (8*b)) & 1ull) << (k*8 + b);
    }
    mb[t] = bits;
  }
  if (t == 0 && tile == 0){ maxIdx[s] = 0; cnt[s] = 0; }
  for (int i = t; i < 4096; i += 256) lp[i] = i;
  for (int i = t; i < 4096; i += 256){
    int ly = i >> 6, lx = i & 63;
    int g = (y0 + ly) * 256 + (x0 + lx);
    comp[sbase + g] = 0;
    sizes[sbase + g] = 0;
  }
  __syncthreads();
  for (int i = t; i < 4096; i += 256){
    int ly = i >> 6, lx = i & 63;
    if (!((mb[ly] >> lx) & 1)) continue;
    if (lx > 0 && ((mb[ly] >> (lx-1)) & 1)) uf_union(lp, i, i - 1);
    if (ly > 0){
      u64 up = mb[ly - 1];
      if (lx > 0  && ((up >> (lx-1)) & 1)) uf_union(lp, i, i - 65);
      if (            ((up >>  lx   ) & 1)) uf_union(lp, i, i - 64);
      if (lx < 63 && ((up >> (lx+1)) & 1)) uf_union(lp, i, i - 63);
    }
  }
  __syncthreads();
  for (int i = t; i < 4096; i += 256){
    int ly = i >> 6, lx = i & 63;
    int g = (y0 + ly) * 256 + (x0 + lx);
    int v = g;
    if ((mb[ly] >> lx) & 1){
      int r = i, p = lp[r];
      while (p != r){ r = p; p = lp[r]; }
      v = (y0 + (r >> 6)) * 256 + (x0 + (r & 63));
    }
    parent[sbase + g] = v;
  }
}

// ---------------- stage 2: unions across tile boundaries only ----------------
__global__ void k_cc_bound(const unsigned char* __restrict__ mask, int* __restrict__ parent){
  int g = blockIdx.x * 256 + threadIdx.x;
  if (g >= BC * HW) return;
  if (!mask[g]) return;
  int s = g >> 16, p = g & (HW - 1);
  int y = p >> 8, x = p & 255;
  int lx = x & 63, ly = y & 63;
  bool bx0 = (lx == 0), by0 = (ly == 0), bx63 = (lx == 63);
  if (!(bx0 || by0 || bx63)) return;
  int* P = parent + ((size_t)s << 16);
  const unsigned char* im = mask + ((size_t)s << 16);
  if (bx0           && x > 0            && im[p - 1])   uf_union(P, p, p - 1);
  if ((bx0 || by0)  && x > 0 && y > 0   && im[p - 257]) uf_union(P, p, p - 257);
  if (by0           && y > 0            && im[p - 256]) uf_union(P, p, p - 256);
  if ((by0 || bx63) && y > 0 && x < 255 && im[p - 255]) uf_union(P, p, p - 255);
}

// ---------------- stage 3: flatten + per-root label(max idx) + size + maxIdx ----------------
__global__ void k_cc_resolve(const unsigned char* __restrict__ mask, int* __restrict__ parent,
                             int* __restrict__ comp, int* __restrict__ sizes,
                             int* __restrict__ maxIdx){
  int g = blockIdx.x * 256 + threadIdx.x;
  if (g >= BC * HW) return;
  int s = g >> 16, p = g & (HW - 1);
  int* P = parent + ((size_t)s << 16);
  bool fg = mask[g] != 0;
  int r = p;
  { int q = P[r]; while (q != r){ r = q; q = P[r]; } }
  P[p] = r;
  u64 act = __ballot(fg);
  if (act == 0) return;
  int lane = threadIdx.x & 63;
  int hi = 63 - __clzll(act);
  if (lane == hi) atomicMax(&maxIdx[s], p);
  int rv = fg ? r : -1;
  int rref = __shfl(rv, hi);
  bool uni = __all((!fg) || (rv == rref));
  size_t sb = (size_t)s << 16;
  if (uni){
    if (lane == hi){
      atomicMax(&comp[sb + rref], p);
      atomicAdd(&sizes[sb + rref], (int)__popcll(act));
    }
  } else if (fg){
    atomicMax(&comp[sb + r], p);
    atomicAdd(&sizes[sb + r], 1);
  }
}

// ---------------- stage 4: compact roots into per-slot list ----------------
__global__ void k_roots(const unsigned char* __restrict__ mask, const int* __restrict__ parent,
                        const int* __restrict__ comp, int* __restrict__ cnt,
                        int* __restrict__ rootArr){
  int g = blockIdx.x * 256 + threadIdx.x;
  if (g >= BC * HW) return;
  int s = g >> 16, p = g & (HW - 1);
  if (!mask[g]) return;
  if (parent[g] != p) return;        // root = min pixel of its component
  if (comp[g] <= 0) return;          // label-0 component excluded (as reference)
  int i = atomicAdd(&cnt[s], 1);
  if (i < MAXROOTS) rootArr[s * MAXROOTS + i] = p;
}

// ---------------- stage 5: top-32 by key=size*label, tie -> smaller label ----------------
__global__ void k_select(const int* __restrict__ cnt, const int* __restrict__ rootArr,
                         const int* __restrict__ comp, const int* __restrict__ sizes,
                         const int* __restrict__ maxIdx,
                         int* __restrict__ rootSel, float* __restrict__ sSel,
                         float* __restrict__ scaleSel){
  int s = blockIdx.x, t = threadIdx.x;
  __shared__ unsigned int used[MAXROOTS / 32];
  __shared__ float rk[256];
  __shared__ int   ri[256];
  __shared__ int   rr[256];
  __shared__ int   stop;
  int n = cnt[s]; if (n > MAXROOTS) n = MAXROOTS;
  for (int i = t; i < MAXROOTS / 32; i += 256) used[i] = 0;
  int mi = maxIdx[s];
  float maxLf = (float)(mi >= 1 ? mi : 1);
  if (t == 0) stop = 0;
  __syncthreads();
  size_t sb = (size_t)s << 16;
  for (int r = 0; r < KCAP; r++){
    float bk = -1.0f; int blab = 0x7fffffff; int bidx = -1;
    for (int i = t; i < n; i += 256){
      if ((used[i >> 5] >> (i & 31)) & 1) continue;
      int rt  = rootArr[s * MAXROOTS + i];
      int lab = comp[sb + rt];
      float key = (float)sizes[sb + rt] * (float)lab;
      if (key > bk || (key == bk && lab < blab)){ bk = key; blab = lab; bidx = i; }
    }
    rk[t] = bk; ri[t] = blab; rr[t] = bidx;
    __syncthreads();
    for (int off = 128; off > 0; off >>= 1){
      if (t < off){
        if (rk[t+off] > rk[t] || (rk[t+off] == rk[t] && ri[t+off] < ri[t])){
          rk[t] = rk[t+off]; ri[t] = ri[t+off]; rr[t] = rr[t+off];
        }
      }
      __syncthreads();
    }
    if (t == 0){
      if (rk[0] > 0.0f && rr[0] >= 0){
        int i = rr[0];
        used[i >> 5] |= (1u << (i & 31));
        int rt  = rootArr[s * MAXROOTS + i];
        int lab = ri[0];
        rootSel[s*KCAP + r]  = rt;
        sSel[s*KCAP + r]     = (float)sizes[sb + rt] * (float)lab / maxLf;
        scaleSel[s*KCAP + r] = (float)lab / maxLf;
      } else {
        for (int q = r; q < KCAP; q++){
          rootSel[s*KCAP + q] = -1;
          sSel[s*KCAP + q] = 0.0f;
          scaleSel[s*KCAP + q] = 0.0f;
        }
        stop = 1;
      }
    }
    __syncthreads();
    if (stop) break;
  }
}

// ---------------- bitmaps of the selected new components ----------------
__global__ void k_newbm(const int* __restrict__ parent, const int* __restrict__ rootSel,
                        u64* __restrict__ newbm){
  int s = blockIdx.x >> 2;                       // 4 blocks per slot
  int w = (blockIdx.x & 3) * 256 + threadIdx.x;  // word index 0..1023
  __shared__ int sel[KCAP];
  if (threadIdx.x < KCAP) sel[threadIdx.x] = rootSel[s*KCAP + threadIdx.x];
  __syncthreads();
  int l[64];
  const int* Ls = parent + ((size_t)s << 16) + (w << 6);
  #pragma unroll
  for (int i = 0; i < 64; i++) l[i] = Ls[i];
  u64* out = newbm + (size_t)s * KCAP * 1024 + w;
  for (int j = 0; j < KCAP; j++){
    int lj = sel[j];
    u64 m = 0;
    if (lj >= 0){
      #pragma unroll
      for (int i = 0; i < 64; i++) m |= ((u64)(l[i] == lj)) << i;
    }
    out[(size_t)j * 1024] = m;
  }
}

// ---------------- overlaps: OV[s][j][k] = scale_j*scaleP_k*popc(new_j & P_k) ----------------
__global__ void k_overlap(const u64* __restrict__ nb, const u64* __restrict__ pb,
                          const float* __restrict__ scaleSel, const float* __restrict__ scaleP,
                          float* __restrict__ OV){
  int s = blockIdx.x >> 5, j = blockIdx.x & 31;
  int t = threadIdx.x;
  float sn = scaleSel[s*KCAP + j];
  float* ovrow = OV + (s*KCAP + j) * KCAP;
  if (sn == 0.0f){
    if (t < KCAP) ovrow[t] = 0.0f;
    return;
  }
  const u64* A = nb + (size_t)(s*KCAP + j) * 1024;
  u64 a[16];
  #pragma unroll
  for (int i = 0; i < 16; i++) a[i] = A[t + 64*i];
  for (int k = 0; k < KCAP; k++){
    float sp = scaleP[s*KCAP + k];
    if (sp == 0.0f){ if (t == 0) ovrow[k] = 0.0f; continue; }
    const u64* Bm = pb + (size_t)(s*KCAP + k) * 1024;
    int c = 0;
    #pragma unroll
    for (int i = 0; i < 16; i++) c += __popcll(a[i] & Bm[t + 64*i]);
    #pragma unroll
    for (int off = 32; off > 0; off >>= 1) c += __shfl_down(c, off);
    if (t == 0) ovrow[k] = sn * sp * (float)c;
  }
}

// ---------------- sequential matching scan (mirrors lax.scan) ----------------
__global__ void k_update(const float* __restrict__ OV, const int* __restrict__ rootSel,
                         const float* __restrict__ sSel, const float* __restrict__ scaleSel,
                         float* __restrict__ bar, int* __restrict__ nArr,
                         float* __restrict__ scaleP,
                         const u64* __restrict__ newbm, u64* __restrict__ Pbm, int t){
  int s = blockIdx.x;
  __shared__ int add_dst[KCAP];
  if (threadIdx.x == 0){
    int n = nArr[s];
    for (int j = 0; j < KCAP; j++){
      add_dst[j] = -1;
      if (rootSel[s*KCAP + j] < 0) continue;    // invalid comp: no-op
      const float* ov = OV + (s*KCAP + j) * KCAP;
      int best = 0; float bv = ov[0];
      for (int k = 1; k < KCAP; k++){ float v = ov[k]; if (v > bv){ bv = v; best = k; } }
      if (bv > 0.0f){                            // matched: overwrite stored slot's bar at t
        bar[(s*KCAP + best)*MAXI + t] = sSel[s*KCAP + j];
      } else if (n < KCAP){                      // add new component
        bar[(s*KCAP + n)*MAXI + t] = sSel[s*KCAP + j];
        scaleP[s*KCAP + n] = scaleSel[s*KCAP + j];
        add_dst[j] = n;
        n++;
      }
    }
    nArr[s] = n;
  }
  __syncthreads();
  for (int j = 0; j < KCAP; j++){
    int d = add_dst[j];
    if (d < 0) continue;
    const u64* src = newbm + (size_t)(s*KCAP + j) * 1024;
    u64* dst       = Pbm   + (size_t)(s*KCAP + d) * 1024;
    for (int w = threadIdx.x; w < 1024; w += blockDim.x) dst[w] = src[w];
  }
}

// ---------------- final loss ----------------
__global__ void k_loss(const float* __restrict__ barP, const float* __restrict__ barT,
                       const int* __restrict__ nP, const int* __restrict__ nT,
                       float* __restrict__ out){
  if (blockIdx.x != 0 || threadIdx.x != 0) return;
  float total = 0.0f;
  for (int s = 0; s < BC; s++){
    int np = nP[s], nt = nT[s];
    for (int k = 0; k < KCAP; k++){
      if (k >= np) continue;
      const float* bp = barP + (s*KCAP + k)*MAXI;
      float pmax = bp[0];
      for (int t = 1; t < MAXI; t++) pmax = fmaxf(pmax, bp[t]);
      if (!(pmax > 0.0f)) pmax = 1.0f;
      float acc = 0.0f;
      for (int t = 0; t < MAXI; t++){
        float tv = (k < nt) ? barT[(s*KCAP + k)*MAXI + t] : 0.0f;
        float d = tv - bp[t];
        acc += d * d;
      }
      total += acc / (pmax * pmax);
    }
  }
  out[0] = total * 0.25f;   // mean over B=4
}

extern "C" void kernel_launch(void* const* d_in, const int* in_sizes, int n_in,
                              void* d_out, int out_size, void* d_ws, size_t ws_size,
                              hipStream_t stream){
  const float* pred = (const float*)d_in[0];
  const float* gum  = (const float*)d_in[1];
  const int*   tgt  = (const int*)d_in[2];
  float* out = (float*)d_out;
  char* ws = (char*)d_ws;
  size_t off = 0;
  auto alloc = [&](size_t bytes)->char*{
    char* p = ws + off;
    off += (bytes + 255) & ~(size_t)255;
    return p;
  };
  unsigned char* maskBase = (unsigned char*)alloc(BC*HW);
  unsigned char* maskA    = (unsigned char*)alloc(BC*HW);
  unsigned char* maskB    = (unsigned char*)alloc(BC*HW);
  int* parent  = (int*)alloc((size_t)BC*HW*4);
  int* comp    = (int*)alloc((size_t)BC*HW*4);
  int* sizesA  = (int*)alloc((size_t)BC*HW*4);
  u64* newbm   = (u64*)alloc((size_t)BC*KCAP*1024*8);
  u64* Pbm     = (u64*)alloc((size_t)BC*KCAP*1024*8);
  int* rootArr = (int*)alloc((size_t)BC*MAXROOTS*4);
  int* cntArr  = (int*)alloc(BC*4);
  float* scaleP   = (float*)alloc(BC*KCAP*4);
  int*   rootSel  = (int*)alloc(BC*KCAP*4);
  float* sSel     = (float*)alloc(BC*KCAP*4);
  float* scaleSel = (float*)alloc(BC*KCAP*4);
  float* OV       = (float*)alloc(BC*KCAP*KCAP*4);
  int*   maxIdx   = (int*)alloc(BC*4);
  float* barP     = (float*)alloc(BC*KCAP*MAXI*4);
  float* barT     = (float*)alloc(BC*KCAP*MAXI*4);
  int*   nP       = (int*)alloc(BC*4);
  int*   nT       = (int*)alloc(BC*4);
  if (off > ws_size) return;   // workspace too small -> fail loudly in validation

  const int PIXBLK = (BC*HW)/256;   // 3072
  const int BINBLK = (NB*HW)/256;   // 1024

  auto process = [&](const unsigned char* m, int t, float* bar, int* nArr){
    k_cc_local<<<BC*16,256,0,stream>>>(m, parent, comp, sizesA, maxIdx, cntArr);
    k_cc_bound<<<PIXBLK,256,0,stream>>>(m, parent);
    k_cc_resolve<<<PIXBLK,256,0,stream>>>(m, parent, comp, sizesA, maxIdx);
    k_roots<<<PIXBLK,256,0,stream>>>(m, parent, comp, cntArr, rootArr);
    k_select<<<BC,256,0,stream>>>(cntArr, rootArr, comp, sizesA, maxIdx, rootSel, sSel, scaleSel);
    k_newbm<<<BC*4,256,0,stream>>>(parent, rootSel, newbm);
    k_overlap<<<BC*KCAP,64,0,stream>>>(newbm, Pbm, scaleSel, scaleP, OV);
    k_update<<<BC,256,0,stream>>>(OV, rootSel, sSel, scaleSel, bar, nArr, scaleP, newbm, Pbm, t);
  };

  for (int pass = 0; pass < 2; pass++){
    float* bar = pass ? barT : barP;
    int* nArr  = pass ? nT : nP;
    hipMemsetAsync(bar, 0, BC*KCAP*MAXI*4, stream);
    hipMemsetAsync(nArr, 0, BC*4, stream);
    hipMemsetAsync(Pbm, 0, (size_t)BC*KCAP*1024*8, stream);
    hipMemsetAsync(scaleP, 0, BC*KCAP*4, stream);
    if (pass == 0) k_bin_pred<<<BINBLK,256,0,stream>>>(pred, gum, maskBase);
    else           k_bin_tgt<<<BINBLK,256,0,stream>>>(tgt, maskBase);
    // schedule: (binary,2), (e1,3), (e2,4), (d1,1), (d2,0)
    process(maskBase, 2, bar, nArr);
    k_morph<<<PIXBLK,256,0,stream>>>(maskBase, maskA, 1);
    process(maskA, 3, bar, nArr);
    k_morph<<<PIXBLK,256,0,stream>>>(maskA, maskB, 1);
    process(maskB, 4, bar, nArr);
    k_morph<<<PIXBLK,256,0,stream>>>(maskBase, maskA, 0);
    process(maskA, 1, bar, nArr);
    k_morph<<<PIXBLK,256,0,stream>>>(maskA, maskB, 0);
    process(maskB, 0, bar, nArr);
  }
  k_loss<<<1,64,0,stream>>>(barP, barT, nP, nT, out);
}

// Round 3
// 1976.093 us; speedup vs baseline: 9.4623x; 1.7430x over previous
//
#include <hip/hip_runtime.h>

#define NB 4
#define NC 3
#define BC 12
#define HW 65536
#define KCAP 32
#define MAXI 5
#define MAXROOTS 16384

typedef unsigned long long u64;

// ---------------- union-find (lock-free, link-to-min, path halving) ----------------
__device__ __forceinline__ int uf_find(int* P, int x){
  while (true){
    int p = P[x];
    if (p == x) return x;
    int gp = P[p];
    if (gp == p) return p;
    P[x] = gp;   // path halving
    x = gp;
  }
}
__device__ __forceinline__ void uf_union(int* P, int a, int b){
  while (true){
    a = uf_find(P, a); b = uf_find(P, b);
    if (a == b) return;
    if (a < b){ int t = a; a = b; b = t; }   // link larger root to smaller
    int old = atomicCAS(&P[a], a, b);
    if (old == a) return;
    a = old;
  }
}

// ---------------- binarization -> bitmaps (wave ballot builds one u64/word) ----------------
__global__ void k_bin_pred(const float* __restrict__ pred, const float* __restrict__ gum,
                           u64* __restrict__ bm, int* __restrict__ cnt){
  int g = blockIdx.x * 256 + threadIdx.x;    // NB*HW threads, all valid
  if (g < BC) cnt[g] = 0;
  int b = g >> 16, p = g & (HW - 1);
  size_t base = (size_t)b * NC * HW + p;
  float v0 = pred[base]        + gum[base];
  float v1 = pred[base + HW]   + gum[base + HW];
  float v2 = pred[base + 2*HW] + gum[base + 2*HW];
  int a = 0; float m = v0;
  if (v1 > m){ m = v1; a = 1; }
  if (v2 > m){ m = v2; a = 2; }
  u64 m0 = __ballot(a == 0);
  u64 m1 = __ballot(a == 1);
  u64 m2 = __ballot(a == 2);
  if ((threadIdx.x & 63) == 0){
    int w = p >> 6;
    bm[(size_t)(b*NC + 0)*1024 + w] = m0;
    bm[(size_t)(b*NC + 1)*1024 + w] = m1;
    bm[(size_t)(b*NC + 2)*1024 + w] = m2;
  }
}

__global__ void k_bin_tgt(const int* __restrict__ tgt, u64* __restrict__ bm,
                          int* __restrict__ cnt){
  int g = blockIdx.x * 256 + threadIdx.x;
  if (g < BC) cnt[g] = 0;
  int b = g >> 16, p = g & (HW - 1);
  int t = tgt[(size_t)b * HW + p];
  u64 m0 = __ballot(t == 0);
  u64 m1 = __ballot(t == 1);
  u64 m2 = __ballot(t == 2);
  if ((threadIdx.x & 63) == 0){
    int w = p >> 6;
    bm[(size_t)(b*NC + 0)*1024 + w] = m0;
    bm[(size_t)(b*NC + 1)*1024 + w] = m1;
    bm[(size_t)(b*NC + 2)*1024 + w] = m2;
  }
}

// ---------------- 5x5 morphology on bitmaps (zero-padded, exact) ----------------
__global__ void k_morph_bm(const u64* __restrict__ in, u64* __restrict__ out,
                           int erode_flag, int* __restrict__ cnt){
  int t = blockIdx.x * 256 + threadIdx.x;    // BC*1024 threads (row-word pairs)
  if (t < BC) cnt[t] = 0;
  if (t >= BC * 1024) return;
  int s = t >> 10, row = (t >> 2) & 255, w = t & 3;
  const u64* bs = in + (size_t)s * 1024;
  u64 res = erode_flag ? ~0ull : 0ull;
  for (int dy = -2; dy <= 2; dy++){
    int y = row + dy;
    if (y < 0 || y > 255){ if (erode_flag) res = 0; continue; }
    const u64* rw = bs + y * 4;
    u64 m = rw[w];
    u64 l = (w > 0) ? rw[w-1] : 0ull;
    u64 r = (w < 3) ? rw[w+1] : 0ull;
    u64 x1l = (m << 1) | (l >> 63);
    u64 x2l = (m << 2) | (l >> 62);
    u64 x1r = (m >> 1) | (r << 63);
    u64 x2r = (m >> 2) | (r << 62);
    u64 h = erode_flag ? (m & x1l & x2l & x1r & x2r)
                       : (m | x1l | x2l | x1r | x2r);
    res = erode_flag ? (res & h) : (res | h);
  }
  out[(size_t)s * 1024 + row * 4 + w] = res;
}

// ---------------- stage 1: per-64x64-tile CC in LDS + per-tile-root aggregates ----------------
__global__ __launch_bounds__(256) void k_cc_local(const u64* __restrict__ bm,
                           int* __restrict__ parent, int* __restrict__ cnt,
                           int* __restrict__ rootL, int* __restrict__ sizeL,
                           int* __restrict__ maxPL){
  __shared__ int lp[4096];
  __shared__ int lsz[4096];
  __shared__ int lmx[4096];
  __shared__ u64 mb[64];
  int s = blockIdx.x >> 4, tile = blockIdx.x & 15;
  int ty = tile >> 2, tx = tile & 3;
  int y0 = ty * 64, x0 = tx * 64;
  int t = threadIdx.x;
  if (t < 64) mb[t] = bm[(size_t)s * 1024 + (y0 + t) * 4 + tx];
  for (int i = t; i < 4096; i += 256){ lp[i] = i; lsz[i] = 0; lmx[i] = 0; }
  __syncthreads();
  for (int i = t; i < 4096; i += 256){
    int ly = i >> 6, lx = i & 63;
    if (!((mb[ly] >> lx) & 1)) continue;
    if (lx > 0 && ((mb[ly] >> (lx-1)) & 1)) uf_union(lp, i, i - 1);
    if (ly > 0){
      u64 up = mb[ly - 1];
      if (lx > 0  && ((up >> (lx-1)) & 1)) uf_union(lp, i, i - 65);
      if (            (up >>  lx   ) & 1 ) uf_union(lp, i, i - 64);
      if (lx < 63 && ((up >> (lx+1)) & 1)) uf_union(lp, i, i - 63);
    }
  }
  __syncthreads();
  size_t sb = (size_t)s << 16;
  for (int i = t; i < 4096; i += 256){
    int ly = i >> 6, lx = i & 63;
    int g = (y0 + ly) * 256 + (x0 + lx);
    int v = g;
    if ((mb[ly] >> lx) & 1){
      int r = i, p = lp[r];
      while (p != r){ r = p; p = lp[r]; }
      v = (y0 + (r >> 6)) * 256 + (x0 + (r & 63));
      atomicAdd(&lsz[r], 1);
      atomicMax(&lmx[r], g);
      if (r != i) lp[i] = r;
    }
    parent[sb + g] = v;
  }
  __syncthreads();
  for (int i = t; i < 4096; i += 256){
    int ly = i >> 6, lx = i & 63;
    if (!((mb[ly] >> lx) & 1)) continue;
    if (lp[i] != i) continue;                 // tile-local root
    int g = (y0 + ly) * 256 + (x0 + lx);
    int idx = atomicAdd(&cnt[s], 1);
    if (idx < MAXROOTS){
      rootL[s*MAXROOTS + idx] = g;
      sizeL[s*MAXROOTS + idx] = lsz[i];
      maxPL[s*MAXROOTS + idx] = lmx[i];
    }
  }
}

// ---------------- stage 2: unions across tile boundaries only (compact index) ----------------
__global__ void k_cc_bound(const u64* __restrict__ bm, int* __restrict__ parent){
  int t = blockIdx.x * 256 + threadIdx.x;    // BC*2304
  if (t >= BC * 2304) return;
  int s = t / 2304, i = t % 2304;
  const u64* m = bm + (size_t)s * 1024;
  int* P = parent + ((size_t)s << 16);
  #define FG(pp) ((m[(pp) >> 6] >> ((pp) & 63)) & 1ull)
  if (i < 768){                                   // horizontal tile seams: ly==0, y>0
    int y = 64 * (i / 256 + 1), x = i & 255, p = y * 256 + x;
    if (FG(p)){
      if (x > 0   && FG(p - 257)) uf_union(P, p, p - 257);
      if (           FG(p - 256)) uf_union(P, p, p - 256);
      if (x < 255 && FG(p - 255)) uf_union(P, p, p - 255);
    }
  } else if (i < 1536){                           // vertical seams: lx==0, x>0
    int j = i - 768;
    int x = 64 * (j / 256 + 1), y = j & 255, p = y * 256 + x;
    if (FG(p)){
      if (           FG(p - 1))   uf_union(P, p, p - 1);
      if (y > 0   && FG(p - 257)) uf_union(P, p, p - 257);
    }
  } else {                                        // lx==63 up-right: x in {63,127,191}
    int j = i - 1536;
    int x = 64 * (j / 256 + 1) - 1, y = j & 255, p = y * 256 + x;
    if (y > 0 && FG(p) && FG(p - 255)) uf_union(P, p, p - 255);
  }
  #undef FG
}

// ---------------- stage 3: resolve tile roots + aggregate + top-32 select (1 block/slot) ----------------
__global__ __launch_bounds__(256) void k_resolve_select(
    int* __restrict__ parent, const int* __restrict__ cnt,
    const int* __restrict__ rootL, const int* __restrict__ sizeL,
    const int* __restrict__ maxPL, int* __restrict__ RA,
    int* __restrict__ sizeF, int* __restrict__ compF,
    int* __restrict__ rootSel, float* __restrict__ sSel, float* __restrict__ scaleSel){
  int s = blockIdx.x, t = threadIdx.x;
  __shared__ unsigned used[MAXROOTS / 32];
  __shared__ float rk[256];
  __shared__ int ri[256], re[256], mred[256];
  __shared__ int stop;
  int n = cnt[s]; if (n > MAXROOTS) n = MAXROOTS;
  size_t sb = (size_t)s << 16;
  int* P = parent + sb;
  // phase 1: find final root per entry, compress, zero aggregates
  for (int e = t; e < n; e += 256){
    int r = rootL[s*MAXROOTS + e];
    int x = r, p = P[x];
    while (p != x){ x = p; p = P[x]; }
    P[r] = x;
    RA[s*MAXROOTS + e] = x;
    sizeF[sb + x] = 0; compF[sb + x] = 0;
  }
  int mymax = 0;
  for (int e = t; e < n; e += 256) mymax = max(mymax, maxPL[s*MAXROOTS + e]);
  mred[t] = mymax;
  for (int i = t; i < MAXROOTS / 32; i += 256) used[i] = 0;
  if (t == 0) stop = 0;
  __syncthreads();
  // phase 2: accumulate per final root
  for (int e = t; e < n; e += 256){
    int R = RA[s*MAXROOTS + e];
    atomicAdd(&sizeF[sb + R], sizeL[s*MAXROOTS + e]);
    atomicMax(&compF[sb + R], maxPL[s*MAXROOTS + e]);
  }
  __syncthreads();
  for (int off = 128; off > 0; off >>= 1){
    if (t < off) mred[t] = max(mred[t], mred[t + off]);
    __syncthreads();
  }
  int mi = mred[0];
  float maxLf = (float)(mi >= 1 ? mi : 1);
  // phase 3: 32 selection rounds; key=size*label, tie -> smaller label
  for (int r = 0; r < KCAP; r++){
    float bk = -1.0f; int blab = 0x7fffffff; int be = -1;
    for (int e = t; e < n; e += 256){
      if ((used[e >> 5] >> (e & 31)) & 1) continue;
      int rt = rootL[s*MAXROOTS + e];
      if (RA[s*MAXROOTS + e] != rt) continue;   // not a final root
      int lab = compF[sb + rt];
      if (lab <= 0) continue;                    // label-0 comp excluded
      float key = (float)sizeF[sb + rt] * (float)lab;
      if (key > bk || (key == bk && lab < blab)){ bk = key; blab = lab; be = e; }
    }
    rk[t] = bk; ri[t] = blab; re[t] = be;
    __syncthreads();
    for (int off = 128; off > 0; off >>= 1){
      if (t < off && (rk[t+off] > rk[t] || (rk[t+off] == rk[t] && ri[t+off] < ri[t]))){
        rk[t] = rk[t+off]; ri[t] = ri[t+off]; re[t] = re[t+off];
      }
      __syncthreads();
    }
    if (t == 0){
      if (rk[0] > 0.0f && re[0] >= 0){
        int e = re[0];
        used[e >> 5] |= 1u << (e & 31);
        int rt = rootL[s*MAXROOTS + e];
        rootSel[s*KCAP + r]  = rt;
        sSel[s*KCAP + r]     = (float)sizeF[sb + rt] * (float)ri[0] / maxLf;
        scaleSel[s*KCAP + r] = (float)ri[0] / maxLf;
      } else {
        for (int q = r; q < KCAP; q++){
          rootSel[s*KCAP + q] = -1; sSel[s*KCAP + q] = 0.0f; scaleSel[s*KCAP + q] = 0.0f;
        }
        stop = 1;
      }
    }
    __syncthreads();
    if (stop) break;
  }
}

// ---------------- bitmaps of selected components via 2-hop root + ballot ----------------
__global__ void k_newbm(const int* __restrict__ parent, const int* __restrict__ rootSel,
                        u64* __restrict__ newbm){
  int g = blockIdx.x * 256 + threadIdx.x;    // BC*HW
  int s = g >> 16, p = g & (HW - 1);
  __shared__ int sel[KCAP];
  if (threadIdx.x < KCAP) sel[threadIdx.x] = rootSel[s*KCAP + threadIdx.x];
  __syncthreads();
  const int* P = parent + ((size_t)s << 16);
  int R = P[P[p]];       // fg: tile root -> final root; bg: p (never equals a fg root)
  u64* outw = newbm + (size_t)s * KCAP * 1024 + (p >> 6);
  for (int j = 0; j < KCAP; j++){
    u64 m = __ballot(R == sel[j]);
    if ((threadIdx.x & 63) == 0) outw[(size_t)j * 1024] = m;
  }
}

// ---------------- overlaps: OV[s][j][k] = scale_j*scaleP_k*popc(new_j & P_k) ----------------
__global__ void k_overlap(const u64* __restrict__ nb, const u64* __restrict__ pb,
                          const float* __restrict__ scaleSel, const float* __restrict__ scaleP,
                          float* __restrict__ OV){
  int s = blockIdx.x >> 5, j = blockIdx.x & 31;
  int t = threadIdx.x;
  float sn = scaleSel[s*KCAP + j];
  float* ovrow = OV + (s*KCAP + j) * KCAP;
  if (sn == 0.0f){
    if (t < KCAP) ovrow[t] = 0.0f;
    return;
  }
  const u64* A = nb + (size_t)(s*KCAP + j) * 1024;
  u64 a[16];
  #pragma unroll
  for (int i = 0; i < 16; i++) a[i] = A[t + 64*i];
  for (int k = 0; k < KCAP; k++){
    float sp = scaleP[s*KCAP + k];
    if (sp == 0.0f){ if (t == 0) ovrow[k] = 0.0f; continue; }
    const u64* Bm = pb + (size_t)(s*KCAP + k) * 1024;
    int c = 0;
    #pragma unroll
    for (int i = 0; i < 16; i++) c += __popcll(a[i] & Bm[t + 64*i]);
    #pragma unroll
    for (int off = 32; off > 0; off >>= 1) c += __shfl_down(c, off);
    if (t == 0) ovrow[k] = sn * sp * (float)c;
  }
}

// ---------------- matching scan (argmax parallel, decisions sequential as lax.scan) ----------------
__global__ void k_update(const float* __restrict__ OV, const int* __restrict__ rootSel,
                         const float* __restrict__ sSel, const float* __restrict__ scaleSel,
                         float* __restrict__ bar, int* __restrict__ nArr,
                         float* __restrict__ scaleP,
                         const u64* __restrict__ newbm, u64* __restrict__ Pbm, int t){
  int s = blockIdx.x;
  __shared__ int add_dst[KCAP];
  __shared__ int bestA[KCAP];
  __shared__ float bvA[KCAP];
  int tid = threadIdx.x;
  if (tid < KCAP){
    const float* ov = OV + (s*KCAP + tid) * KCAP;
    int best = 0; float bv = ov[0];
    for (int k = 1; k < KCAP; k++){ float v = ov[k]; if (v > bv){ bv = v; best = k; } }
    bestA[tid] = best; bvA[tid] = bv;
  }
  __syncthreads();
  if (tid == 0){
    int n = nArr[s];
    for (int j = 0; j < KCAP; j++){
      add_dst[j] = -1;
      if (rootSel[s*KCAP + j] < 0) continue;
      if (bvA[j] > 0.0f){
        bar[(s*KCAP + bestA[j])*MAXI + t] = sSel[s*KCAP + j];
      } else if (n < KCAP){
        bar[(s*KCAP + n)*MAXI + t] = sSel[s*KCAP + j];
        scaleP[s*KCAP + n] = scaleSel[s*KCAP + j];
        add_dst[j] = n;
        n++;
      }
    }
    nArr[s] = n;
  }
  __syncthreads();
  for (int j = 0; j < KCAP; j++){
    int d = add_dst[j];
    if (d < 0) continue;
    const u64* src = newbm + (size_t)(s*KCAP + j) * 1024;
    u64* dst       = Pbm   + (size_t)(s*KCAP + d) * 1024;
    for (int w = tid; w < 1024; w += blockDim.x) dst[w] = src[w];
  }
}

// ---------------- final loss ----------------
__global__ void k_loss(const float* __restrict__ barP, const float* __restrict__ barT,
                       const int* __restrict__ nP, const int* __restrict__ nT,
                       float* __restrict__ out){
  if (blockIdx.x != 0 || threadIdx.x != 0) return;
  float total = 0.0f;
  for (int s = 0; s < BC; s++){
    int np = nP[s], nt = nT[s];
    for (int k = 0; k < KCAP; k++){
      if (k >= np) continue;
      const float* bp = barP + (s*KCAP + k)*MAXI;
      float pmax = bp[0];
      for (int t = 1; t < MAXI; t++) pmax = fmaxf(pmax, bp[t]);
      if (!(pmax > 0.0f)) pmax = 1.0f;
      float acc = 0.0f;
      for (int t = 0; t < MAXI; t++){
        float tv = (k < nt) ? barT[(s*KCAP + k)*MAXI + t] : 0.0f;
        float d = tv - bp[t];
        acc += d * d;
      }
      total += acc / (pmax * pmax);
    }
  }
  out[0] = total * 0.25f;   // mean over B=4
}

extern "C" void kernel_launch(void* const* d_in, const int* in_sizes, int n_in,
                              void* d_out, int out_size, void* d_ws, size_t ws_size,
                              hipStream_t stream){
  const float* pred = (const float*)d_in[0];
  const float* gum  = (const float*)d_in[1];
  const int*   tgt  = (const int*)d_in[2];
  float* out = (float*)d_out;
  char* ws = (char*)d_ws;
  size_t off = 0;
  auto alloc = [&](size_t bytes)->char*{
    char* p = ws + off;
    off += (bytes + 255) & ~(size_t)255;
    return p;
  };
  u64* bmBase = (u64*)alloc((size_t)BC*1024*8);
  u64* bmA    = (u64*)alloc((size_t)BC*1024*8);
  u64* bmB    = (u64*)alloc((size_t)BC*1024*8);
  int* parent = (int*)alloc((size_t)BC*HW*4);
  int* sizeF  = (int*)alloc((size_t)BC*HW*4);
  int* compF  = (int*)alloc((size_t)BC*HW*4);
  int* rootL  = (int*)alloc((size_t)BC*MAXROOTS*4);
  int* sizeL  = (int*)alloc((size_t)BC*MAXROOTS*4);
  int* maxPL  = (int*)alloc((size_t)BC*MAXROOTS*4);
  int* RA     = (int*)alloc((size_t)BC*MAXROOTS*4);
  u64* newbm  = (u64*)alloc((size_t)BC*KCAP*1024*8);
  u64* Pbm    = (u64*)alloc((size_t)BC*KCAP*1024*8);
  int* cntArr = (int*)alloc(BC*4);
  float* scaleP   = (float*)alloc(BC*KCAP*4);
  int*   rootSel  = (int*)alloc(BC*KCAP*4);
  float* sSel     = (float*)alloc(BC*KCAP*4);
  float* scaleSel = (float*)alloc(BC*KCAP*4);
  float* OV       = (float*)alloc(BC*KCAP*KCAP*4);
  float* barP     = (float*)alloc(BC*KCAP*MAXI*4);
  float* barT     = (float*)alloc(BC*KCAP*MAXI*4);
  int*   nP       = (int*)alloc(BC*4);
  int*   nT       = (int*)alloc(BC*4);
  if (off > ws_size) return;

  const int PIXBLK = (BC*HW)/256;     // 3072
  const int BINBLK = (NB*HW)/256;     // 1024
  const int BNDBLK = (BC*2304 + 255)/256;   // 108
  const int MRPBLK = (BC*1024 + 255)/256;   // 48

  auto process = [&](const u64* m, int t, float* bar, int* nArr){
    k_cc_local<<<BC*16,256,0,stream>>>(m, parent, cntArr, rootL, sizeL, maxPL);
    k_cc_bound<<<BNDBLK,256,0,stream>>>(m, parent);
    k_resolve_select<<<BC,256,0,stream>>>(parent, cntArr, rootL, sizeL, maxPL,
                                          RA, sizeF, compF, rootSel, sSel, scaleSel);
    k_newbm<<<PIXBLK,256,0,stream>>>(parent, rootSel, newbm);
    k_overlap<<<BC*KCAP,64,0,stream>>>(newbm, Pbm, scaleSel, scaleP, OV);
    k_update<<<BC,256,0,stream>>>(OV, rootSel, sSel, scaleSel, bar, nArr, scaleP, newbm, Pbm, t);
  };

  for (int pass = 0; pass < 2; pass++){
    float* bar = pass ? barT : barP;
    int* nArr  = pass ? nT : nP;
    hipMemsetAsync(bar, 0, BC*KCAP*MAXI*4, stream);
    hipMemsetAsync(nArr, 0, BC*4, stream);
    hipMemsetAsync(scaleP, 0, BC*KCAP*4, stream);
    if (pass == 0) k_bin_pred<<<BINBLK,256,0,stream>>>(pred, gum, bmBase, cntArr);
    else           k_bin_tgt<<<BINBLK,256,0,stream>>>(tgt, bmBase, cntArr);
    // schedule: (binary,2), (e1,3), (e2,4), (d1,1), (d2,0)
    process(bmBase, 2, bar, nArr);
    k_morph_bm<<<MRPBLK,256,0,stream>>>(bmBase, bmA, 1, cntArr);
    process(bmA, 3, bar, nArr);
    k_morph_bm<<<MRPBLK,256,0,stream>>>(bmA, bmB, 1, cntArr);
    process(bmB, 4, bar, nArr);
    k_morph_bm<<<MRPBLK,256,0,stream>>>(bmBase, bmA, 0, cntArr);
    process(bmA, 1, bar, nArr);
    k_morph_bm<<<MRPBLK,256,0,stream>>>(bmA, bmB, 0, cntArr);
    process(bmB, 0, bar, nArr);
  }
  k_loss<<<1,64,0,stream>>>(barP, barT, nP, nT, out);
}

// Round 4
// 780.009 us; speedup vs baseline: 23.9720x; 2.5334x over previous
//
#include <hip/hip_runtime.h>

#define NB 4
#define NC 3
#define BC 12
#define HW 65536
#define KCAP 32
#define MAXI 5
#define ROOTCAP 2048
#define NSLOT 120     // 10 steps x 12 (b,c) slots
#define NCH 24        // chain slots: 2 passes x 12

typedef unsigned long long u64;

// ---------------- union-find (lock-free, link-to-min, path halving) ----------------
__device__ __forceinline__ int uf_find(int* P, int x){
  while (true){
    int p = P[x];
    if (p == x) return x;
    int gp = P[p];
    if (gp == p) return p;
    P[x] = gp;   // path halving
    x = gp;
  }
}
__device__ __forceinline__ void uf_union(int* P, int a, int b){
  while (true){
    a = uf_find(P, a); b = uf_find(P, b);
    if (a == b) return;
    if (a < b){ int t = a; a = b; b = t; }   // link larger root to smaller
    int old = atomicCAS(&P[a], a, b);
    if (old == a) return;
    a = old;
  }
}

// ---------------- binarization: both base masks (pred -> g=0, tgt -> g=5) ----------------
__global__ void k_bin(const float* __restrict__ pred, const float* __restrict__ gum,
                      const int* __restrict__ tgt, u64* __restrict__ bmAll,
                      int* __restrict__ cnt){
  int g = blockIdx.x * 256 + threadIdx.x;    // NB*HW threads
  if (g < NSLOT) cnt[g] = 0;
  int b = g >> 16, p = g & (HW - 1);
  size_t base = (size_t)b * NC * HW + p;
  float v0 = pred[base]        + gum[base];
  float v1 = pred[base + HW]   + gum[base + HW];
  float v2 = pred[base + 2*HW] + gum[base + 2*HW];
  int a = 0; float m = v0;
  if (v1 > m){ m = v1; a = 1; }
  if (v2 > m){ m = v2; a = 2; }
  int tg = tgt[(size_t)b * HW + p];
  u64 p0 = __ballot(a == 0), p1 = __ballot(a == 1), p2 = __ballot(a == 2);
  u64 t0 = __ballot(tg == 0), t1 = __ballot(tg == 1), t2 = __ballot(tg == 2);
  if ((threadIdx.x & 63) == 0){
    int w = p >> 6;
    int sp = b * NC;                       // pass0 base: step g=0
    bmAll[(size_t)(sp + 0) * 1024 + w] = p0;
    bmAll[(size_t)(sp + 1) * 1024 + w] = p1;
    bmAll[(size_t)(sp + 2) * 1024 + w] = p2;
    int st = 60 + b * NC;                  // pass1 base: step g=5
    bmAll[(size_t)(st + 0) * 1024 + w] = t0;
    bmAll[(size_t)(st + 1) * 1024 + w] = t1;
    bmAll[(size_t)(st + 2) * 1024 + w] = t2;
  }
}

// ---------------- 5x5 morphology on bitmaps: 4 independent jobs per launch ----------------
__global__ void k_morph4(const u64* __restrict__ bmAll, u64* __restrict__ bmAllW,
                         int4 srcs, int4 dsts, int4 flgs){
  int t = blockIdx.x * 256 + threadIdx.x;  // 4 * 12 * 1024 = 49152
  int job = t / 12288, rest = t % 12288;
  int s = rest >> 10, word = rest & 1023;
  int row = word >> 2, w = word & 3;
  int srcG = job == 0 ? srcs.x : job == 1 ? srcs.y : job == 2 ? srcs.z : srcs.w;
  int dstG = job == 0 ? dsts.x : job == 1 ? dsts.y : job == 2 ? dsts.z : dsts.w;
  int er   = job == 0 ? flgs.x : job == 1 ? flgs.y : job == 2 ? flgs.z : flgs.w;
  const u64* bs = bmAll + (size_t)(srcG * BC + s) * 1024;
  u64 res = er ? ~0ull : 0ull;
  for (int dy = -2; dy <= 2; dy++){
    int y = row + dy;
    if (y < 0 || y > 255){ if (er) res = 0; continue; }
    const u64* rw = bs + y * 4;
    u64 m = rw[w];
    u64 l = (w > 0) ? rw[w-1] : 0ull;
    u64 r = (w < 3) ? rw[w+1] : 0ull;
    u64 x1l = (m << 1) | (l >> 63);
    u64 x2l = (m << 2) | (l >> 62);
    u64 x1r = (m >> 1) | (r << 63);
    u64 x2r = (m >> 2) | (r << 62);
    u64 h = er ? (m & x1l & x2l & x1r & x2r) : (m | x1l | x2l | x1r | x2r);
    res = er ? (res & h) : (res | h);
  }
  bmAllW[(size_t)(dstG * BC + s) * 1024 + word] = res;
}

// ---------------- stage 1: per-64x64-tile CC in LDS + per-tile-root aggregates ----------------
__global__ __launch_bounds__(256) void k_cc_local(const u64* __restrict__ bmAll,
                           int* __restrict__ parent, int* __restrict__ cnt,
                           int* __restrict__ rootL, int* __restrict__ sizeL,
                           int* __restrict__ maxPL){
  __shared__ int lp[4096];
  __shared__ int lsz[4096];
  __shared__ int lmx[4096];
  __shared__ u64 mb[64];
  int u = blockIdx.x >> 4, tile = blockIdx.x & 15;
  int ty = tile >> 2, tx = tile & 3;
  int y0 = ty * 64, x0 = tx * 64;
  int t = threadIdx.x;
  if (t < 64) mb[t] = bmAll[(size_t)u * 1024 + (y0 + t) * 4 + tx];
  for (int i = t; i < 4096; i += 256){ lp[i] = i; lsz[i] = 0; lmx[i] = 0; }
  __syncthreads();
  for (int i = t; i < 4096; i += 256){
    int ly = i >> 6, lx = i & 63;
    if (!((mb[ly] >> lx) & 1)) continue;
    if (lx > 0 && ((mb[ly] >> (lx-1)) & 1)) uf_union(lp, i, i - 1);
    if (ly > 0){
      u64 up = mb[ly - 1];
      if (lx > 0  && ((up >> (lx-1)) & 1)) uf_union(lp, i, i - 65);
      if (            (up >>  lx   ) & 1 ) uf_union(lp, i, i - 64);
      if (lx < 63 && ((up >> (lx+1)) & 1)) uf_union(lp, i, i - 63);
    }
  }
  __syncthreads();
  size_t sb = (size_t)u << 16;
  for (int i = t; i < 4096; i += 256){
    int ly = i >> 6, lx = i & 63;
    int g = (y0 + ly) * 256 + (x0 + lx);
    int v = g;
    if ((mb[ly] >> lx) & 1){
      int r = i, p = lp[r];
      while (p != r){ r = p; p = lp[r]; }
      v = (y0 + (r >> 6)) * 256 + (x0 + (r & 63));
      atomicAdd(&lsz[r], 1);
      atomicMax(&lmx[r], g);
      if (r != i) lp[i] = r;
    }
    parent[sb + g] = v;
  }
  __syncthreads();
  for (int i = t; i < 4096; i += 256){
    int ly = i >> 6, lx = i & 63;
    if (!((mb[ly] >> lx) & 1)) continue;
    if (lp[i] != i) continue;                 // tile-local root
    int g = (y0 + ly) * 256 + (x0 + lx);
    int idx = atomicAdd(&cnt[u], 1);
    if (idx < ROOTCAP){
      rootL[u*ROOTCAP + idx] = g;
      sizeL[u*ROOTCAP + idx] = lsz[i];
      maxPL[u*ROOTCAP + idx] = lmx[i];
    }
  }
}

// ---------------- stage 2: unions across tile boundaries only ----------------
__global__ void k_cc_bound(const u64* __restrict__ bmAll, int* __restrict__ parent){
  int t = blockIdx.x * 256 + threadIdx.x;    // NSLOT*2304
  if (t >= NSLOT * 2304) return;
  int u = t / 2304, i = t % 2304;
  const u64* m = bmAll + (size_t)u * 1024;
  int* P = parent + ((size_t)u << 16);
  #define FG(pp) ((m[(pp) >> 6] >> ((pp) & 63)) & 1ull)
  if (i < 768){                                   // horizontal seams: ly==0, y>0
    int y = 64 * (i / 256 + 1), x = i & 255, p = y * 256 + x;
    if (FG(p)){
      if (x > 0   && FG(p - 257)) uf_union(P, p, p - 257);
      if (           FG(p - 256)) uf_union(P, p, p - 256);
      if (x < 255 && FG(p - 255)) uf_union(P, p, p - 255);
    }
  } else if (i < 1536){                           // vertical seams: lx==0, x>0
    int j = i - 768;
    int x = 64 * (j / 256 + 1), y = j & 255, p = y * 256 + x;
    if (FG(p)){
      if (           FG(p - 1))   uf_union(P, p, p - 1);
      if (y > 0   && FG(p - 257)) uf_union(P, p, p - 257);
    }
  } else {                                        // lx==63 up-right
    int j = i - 1536;
    int x = 64 * (j / 256 + 1) - 1, y = j & 255, p = y * 256 + x;
    if (y > 0 && FG(p) && FG(p - 255)) uf_union(P, p, p - 255);
  }
  #undef FG
}

// ---------------- stage 3: resolve + aggregate + top-32, all in LDS (1 block/slot) ----------------
__global__ __launch_bounds__(256) void k_resolve_select(
    int* __restrict__ parent, const int* __restrict__ cnt,
    const int* __restrict__ rootL, const int* __restrict__ sizeL,
    const int* __restrict__ maxPL,
    int* __restrict__ rootSel, float* __restrict__ sSel, float* __restrict__ scaleSel){
  int u = blockIdx.x, t = threadIdx.x;
  __shared__ int eR[ROOTCAP], eS[ROOTCAP], eM[ROOTCAP], eRA[ROOTCAP];
  __shared__ int aS[ROOTCAP], aM[ROOTCAP];
  __shared__ int fIdx[ROOTCAP];
  __shared__ int nfS;
  int n = cnt[u]; if (n > ROOTCAP) n = ROOTCAP;
  for (int e = t; e < n; e += 256){
    eR[e] = rootL[u*ROOTCAP + e];
    eS[e] = sizeL[u*ROOTCAP + e];
    eM[e] = maxPL[u*ROOTCAP + e];
  }
  if (t == 0) nfS = 0;
  __syncthreads();
  int* P = parent + ((size_t)u << 16);
  for (int e = t; e < n; e += 256){
    int x = eR[e], p = P[x];
    while (p != x){ x = p; p = P[x]; }
    P[eR[e]] = x;                    // compress ALL tile roots -> final root
    eRA[e] = x;
  }
  __syncthreads();
  for (int f = t; f < n; f += 256){  // aggregate per final root
    if (eRA[f] != eR[f]) continue;
    int R = eR[f], ssum = 0, mmax = 0;
    for (int e = 0; e < n; e++){
      if (eRA[e] == R){ ssum += eS[e]; mmax = max(mmax, eM[e]); }
    }
    aS[f] = ssum; aM[f] = mmax;
  }
  __syncthreads();
  for (int f = t; f < n; f += 256){  // compact final comps with label > 0
    if (eRA[f] == eR[f] && aM[f] > 0){
      int i = atomicAdd(&nfS, 1);
      fIdx[i] = f;
    }
  }
  __syncthreads();
  int nf = nfS;
  if (t >= 64) return;
  int lane = t;
  for (int i = lane; i < nf; i += 64) eRA[fIdx[i]] = -1;  // reuse eRA[f] as used flag (-1 = free)
  int mm = 0;
  for (int i = lane; i < nf; i += 64) mm = max(mm, aM[fIdx[i]]);
  #pragma unroll
  for (int off = 32; off > 0; off >>= 1) mm = max(mm, __shfl_xor(mm, off));
  float maxLf = (float)(mm >= 1 ? mm : 1);
  for (int r = 0; r < KCAP; r++){
    float bk = -1.0f; int blab = 0x7fffffff; int bi = -1;
    for (int i = lane; i < nf; i += 64){
      int f = fIdx[i];
      if (eRA[f] >= 0) continue;          // used
      int lab = aM[f];
      float key = (float)aS[f] * (float)lab;
      if (key > bk || (key == bk && lab < blab)){ bk = key; blab = lab; bi = i; }
    }
    #pragma unroll
    for (int off = 32; off > 0; off >>= 1){
      float ok_ = __shfl_xor(bk, off);
      int ol = __shfl_xor(blab, off), oi = __shfl_xor(bi, off);
      if (ok_ > bk || (ok_ == bk && ol < blab)){ bk = ok_; blab = ol; bi = oi; }
    }
    if (bk > 0.0f && bi >= 0){
      int f = fIdx[bi];
      eRA[f] = 1;                          // all lanes write same value
      if (lane == 0){
        rootSel[u*KCAP + r]  = eR[f];
        sSel[u*KCAP + r]     = (float)aS[f] * (float)blab / maxLf;
        scaleSel[u*KCAP + r] = (float)blab / maxLf;
      }
    } else {
      if (lane == 0){
        for (int q = r; q < KCAP; q++){
          rootSel[u*KCAP + q] = -1; sSel[u*KCAP + q] = 0.0f; scaleSel[u*KCAP + q] = 0.0f;
        }
      }
      break;
    }
  }
}

// ---------------- bitmaps of selected comps, both passes of chain step k ----------------
__global__ void k_newbm(const int* __restrict__ parent, const int* __restrict__ rootSel,
                        u64* __restrict__ newbm, int kstep){
  int idx = blockIdx.x * 256 + threadIdx.x;   // NCH*HW
  int w = idx >> 16, p = idx & (HW - 1);
  int pass = w / 12, s = w % 12;
  int u = (pass * 5 + kstep) * BC + s;
  __shared__ int sel[KCAP];
  if (threadIdx.x < KCAP) sel[threadIdx.x] = rootSel[u*KCAP + threadIdx.x];
  __syncthreads();
  const int* P = parent + ((size_t)u << 16);
  int R = P[P[p]];
  u64* outw = newbm + (size_t)w * KCAP * 1024 + (p >> 6);
  for (int j = 0; j < KCAP; j++){
    u64 m = __ballot(R == sel[j]);
    if ((threadIdx.x & 63) == 0) outw[(size_t)j * 1024] = m;
  }
}

// ---------------- overlaps ----------------
__global__ void k_overlap(const u64* __restrict__ nb, const u64* __restrict__ pb,
                          const float* __restrict__ scaleSel, const float* __restrict__ scaleP,
                          float* __restrict__ OV, int kstep){
  int w = blockIdx.x >> 5, j = blockIdx.x & 31;
  int pass = w / 12, s = w % 12;
  int u = (pass * 5 + kstep) * BC + s;
  int t = threadIdx.x;
  float sn = scaleSel[u*KCAP + j];
  float* ovrow = OV + (w*KCAP + j) * KCAP;
  if (sn == 0.0f){
    if (t < KCAP) ovrow[t] = 0.0f;
    return;
  }
  const u64* A = nb + (size_t)(w*KCAP + j) * 1024;
  u64 a[16];
  #pragma unroll
  for (int i = 0; i < 16; i++) a[i] = A[t + 64*i];
  for (int k = 0; k < KCAP; k++){
    float sp = scaleP[w*KCAP + k];
    if (sp == 0.0f){ if (t == 0) ovrow[k] = 0.0f; continue; }
    const u64* Bm = pb + (size_t)(w*KCAP + k) * 1024;
    int c = 0;
    #pragma unroll
    for (int i = 0; i < 16; i++) c += __popcll(a[i] & Bm[t + 64*i]);
    #pragma unroll
    for (int off = 32; off > 0; off >>= 1) c += __shfl_down(c, off);
    if (t == 0) ovrow[k] = sn * sp * (float)c;
  }
}

// ---------------- matching scan (sequential as lax.scan), both passes ----------------
__global__ void k_update(const float* __restrict__ OV, const int* __restrict__ rootSel,
                         const float* __restrict__ sSel, const float* __restrict__ scaleSel,
                         float* __restrict__ barP, float* __restrict__ barT,
                         int* __restrict__ n24, float* __restrict__ scaleP,
                         const u64* __restrict__ newbm, u64* __restrict__ Pbm,
                         int kstep, int tval){
  int w = blockIdx.x;
  int pass = w / 12, s = w % 12;
  int u = (pass * 5 + kstep) * BC + s;
  float* bar = (pass ? barT : barP) + s * KCAP * MAXI;
  __shared__ int add_dst[KCAP];
  __shared__ int bestA[KCAP];
  __shared__ float bvA[KCAP];
  int tid = threadIdx.x;
  if (tid < KCAP){
    const float* ov = OV + (w*KCAP + tid) * KCAP;
    int best = 0; float bv = ov[0];
    for (int k = 1; k < KCAP; k++){ float v = ov[k]; if (v > bv){ bv = v; best = k; } }
    bestA[tid] = best; bvA[tid] = bv;
  }
  __syncthreads();
  if (tid == 0){
    int n = n24[w];
    for (int j = 0; j < KCAP; j++){
      add_dst[j] = -1;
      if (rootSel[u*KCAP + j] < 0) continue;
      if (bvA[j] > 0.0f){
        bar[bestA[j]*MAXI + tval] = sSel[u*KCAP + j];
      } else if (n < KCAP){
        bar[n*MAXI + tval] = sSel[u*KCAP + j];
        scaleP[w*KCAP + n] = scaleSel[u*KCAP + j];
        add_dst[j] = n;
        n++;
      }
    }
    n24[w] = n;
  }
  __syncthreads();
  for (int j = 0; j < KCAP; j++){
    int d = add_dst[j];
    if (d < 0) continue;
    const u64* src = newbm + (size_t)(w*KCAP + j) * 1024;
    u64* dst       = Pbm   + (size_t)(w*KCAP + d) * 1024;
    for (int x = tid; x < 1024; x += blockDim.x) dst[x] = src[x];
  }
}

// ---------------- final loss ----------------
__global__ void k_loss(const float* __restrict__ barP, const float* __restrict__ barT,
                       const int* __restrict__ n24, float* __restrict__ out){
  if (blockIdx.x != 0 || threadIdx.x != 0) return;
  float total = 0.0f;
  for (int s = 0; s < BC; s++){
    int np = n24[s], nt = n24[12 + s];
    for (int k = 0; k < KCAP; k++){
      if (k >= np) continue;
      const float* bp = barP + (s*KCAP + k)*MAXI;
      float pmax = bp[0];
      for (int t = 1; t < MAXI; t++) pmax = fmaxf(pmax, bp[t]);
      if (!(pmax > 0.0f)) pmax = 1.0f;
      float acc = 0.0f;
      for (int t = 0; t < MAXI; t++){
        float tv = (k < nt) ? barT[(s*KCAP + k)*MAXI + t] : 0.0f;
        float d = tv - bp[t];
        acc += d * d;
      }
      total += acc / (pmax * pmax);
    }
  }
  out[0] = total * 0.25f;   // mean over B=4
}

extern "C" void kernel_launch(void* const* d_in, const int* in_sizes, int n_in,
                              void* d_out, int out_size, void* d_ws, size_t ws_size,
                              hipStream_t stream){
  const float* pred = (const float*)d_in[0];
  const float* gum  = (const float*)d_in[1];
  const int*   tgt  = (const int*)d_in[2];
  float* out = (float*)d_out;
  char* ws = (char*)d_ws;
  size_t off = 0;
  auto alloc = [&](size_t bytes)->char*{
    char* p = ws + off;
    off += (bytes + 255) & ~(size_t)255;
    return p;
  };
  u64* bmAll  = (u64*)alloc((size_t)NSLOT*1024*8);          // 0.94 MB
  int* parent = (int*)alloc((size_t)NSLOT*HW*4);            // 30 MB
  int* rootL  = (int*)alloc((size_t)NSLOT*ROOTCAP*4);
  int* sizeL  = (int*)alloc((size_t)NSLOT*ROOTCAP*4);
  int* maxPL  = (int*)alloc((size_t)NSLOT*ROOTCAP*4);
  int* cntArr = (int*)alloc(NSLOT*4);
  int*   rootSel  = (int*)alloc(NSLOT*KCAP*4);
  float* sSel     = (float*)alloc(NSLOT*KCAP*4);
  float* scaleSel = (float*)alloc(NSLOT*KCAP*4);
  u64* newbm  = (u64*)alloc((size_t)NCH*KCAP*1024*8);       // 6 MB
  u64* Pbm    = (u64*)alloc((size_t)NCH*KCAP*1024*8);       // 6 MB
  float* OV   = (float*)alloc((size_t)NCH*KCAP*KCAP*4);
  // contiguous zero region: barP | barT | scaleP | n24
  size_t zbytes = (size_t)(BC*KCAP*MAXI*2 + NCH*KCAP)*4 + NCH*4;
  char* zreg = alloc(zbytes);
  float* barP   = (float*)zreg;
  float* barT   = barP + BC*KCAP*MAXI;
  float* scaleP = barT + BC*KCAP*MAXI;
  int*   n24    = (int*)(scaleP + NCH*KCAP);
  if (off > ws_size) return;

  hipMemsetAsync(zreg, 0, zbytes, stream);
  // binarize both passes' base masks (steps g=0 and g=5); zero cnt
  k_bin<<<(NB*HW)/256,256,0,stream>>>(pred, gum, tgt, bmAll, cntArr);
  // morphology rounds: e1/d1 then e2/d2, both passes batched
  k_morph4<<<192,256,0,stream>>>(bmAll, bmAll, make_int4(0,0,5,5), make_int4(1,3,6,8), make_int4(1,0,1,0));
  k_morph4<<<192,256,0,stream>>>(bmAll, bmAll, make_int4(1,3,6,8), make_int4(2,4,7,9), make_int4(1,0,1,0));
  // batched CC over all 120 slots
  k_cc_local<<<NSLOT*16,256,0,stream>>>(bmAll, parent, cntArr, rootL, sizeL, maxPL);
  k_cc_bound<<<(NSLOT*2304 + 255)/256,256,0,stream>>>(bmAll, parent);
  k_resolve_select<<<NSLOT,256,0,stream>>>(parent, cntArr, rootL, sizeL, maxPL,
                                           rootSel, sSel, scaleSel);
  // sequential matching chain: 5 steps, both passes per step
  const int tvals[5] = {2, 3, 4, 1, 0};
  for (int k = 0; k < 5; k++){
    k_newbm<<<(NCH*HW)/256,256,0,stream>>>(parent, rootSel, newbm, k);
    k_overlap<<<NCH*KCAP,64,0,stream>>>(newbm, Pbm, scaleSel, scaleP, OV, k);
    k_update<<<NCH,256,0,stream>>>(OV, rootSel, sSel, scaleSel, barP, barT,
                                   n24, scaleP, newbm, Pbm, k, tvals[k]);
  }
  k_loss<<<1,64,0,stream>>>(barP, barT, n24, out);
}